// Round 16
// baseline (95.444 us; speedup 1.0000x reference)
//
#include <hip/hip_runtime.h>
#include <hip/hip_bf16.h>

typedef __bf16 bf16_t;
typedef __attribute__((ext_vector_type(4))) float f32x4;
typedef __attribute__((ext_vector_type(8))) __bf16 bf16x8;
typedef __attribute__((ext_vector_type(4))) __bf16 bf16x4;
typedef __attribute__((ext_vector_type(2))) __bf16 bf16x2;

#define NQ    1024
#define DIM   384
#define NHEAD 8
#define HDIM  48
#define HALFD 24
#define NKEY  196
#define HKEY  98     // keys per half-block (levels 0-1 | levels 2-3)
#define TOTAL 5440   // 64*64 + 32*32 + 16*16 + 8*8

typedef __attribute__((address_space(1))) void gas_void;
typedef __attribute__((address_space(3))) void las_void;
__device__ __forceinline__ void gload16(const void* g, void* l) {
    __builtin_amdgcn_global_load_lds((gas_void*)g, (las_void*)l, 16, 0, 0);
}

// ---------------------------------------------------------------------------
// prep: fmaps fp32->bf16 (blocks [0,nfm)), weights (nfm..nfm+575),
// sincos tables (nfm+576), fused LayerNorm (nfm+577.., 4 rows/blk)
// ---------------------------------------------------------------------------
__global__ __launch_bounds__(256) void prep_kernel(
    const float* __restrict__ fmaps, bf16_t* __restrict__ fm_bf, int nfm,
    const float* __restrict__ wq, const float* __restrict__ wkv,
    const float* __restrict__ wout, bf16_t* __restrict__ wq_bf,
    bf16_t* __restrict__ wkv_bf, bf16_t* __restrict__ wout_bf,
    float2* __restrict__ tabS, float2* __restrict__ tabL,
    const float* __restrict__ query, const float* __restrict__ nw,
    const float* __restrict__ nb, bf16_t* __restrict__ x_ln)
{
    int bid = blockIdx.x;
    if (bid < nfm) {
        int i = bid * 256 + threadIdx.x;
        float4 v = ((const float4*)fmaps)[i];
        bf16x4 o = { (bf16_t)v.x, (bf16_t)v.y, (bf16_t)v.z, (bf16_t)v.w };
        ((bf16x4*)fm_bf)[i] = o;
        return;
    }
    int wb = bid - nfm;
    if (wb < 576) {
        int i = wb * 256 + threadIdx.x;
        const float* src; bf16_t* dst; int off;
        if (i < 36864)       { src = wq;   dst = wq_bf;   off = i; }
        else if (i < 110592) { src = wkv;  dst = wkv_bf;  off = i - 36864; }
        else                 { src = wout; dst = wout_bf; off = i - 110592; }
        float4 v = ((const float4*)src)[off];
        bf16x4 o = { (bf16_t)v.x, (bf16_t)v.y, (bf16_t)v.z, (bf16_t)v.w };
        ((bf16x4*)dst)[off] = o;
        return;
    }
    if (wb == 576) {
        int t = threadIdx.x;
        if (t < 512) {
            int i = t >> 3, f = t & 7;
            float fr = powf(10.f, -(float)f / 8.f);
            float s, c; sincosf((float)i * fr, &s, &c);
            tabS[t] = make_float2(c, s);
        } else if (t < 544) {
            int u = t - 512; int l = u >> 3, f = u & 7;
            float fr = powf(10.f, (float)f / 8.f);
            float s, c; sincosf((float)l * fr, &s, &c);
            tabL[u] = make_float2(c, s);
        }
        return;
    }
    // LayerNorm: 4 rows per block, one wave per row
    {
        int n = (wb - 577) * 4 + (threadIdx.x >> 6);
        int lane = threadIdx.x & 63;
        const float* row = query + (size_t)n * DIM;
        float v[6], s = 0.f, s2 = 0.f;
#pragma unroll
        for (int i = 0; i < 6; ++i) {
            v[i] = row[lane + i * 64];
            s += v[i]; s2 += v[i] * v[i];
        }
#pragma unroll
        for (int m = 32; m; m >>= 1) { s += __shfl_xor(s, m); s2 += __shfl_xor(s2, m); }
        float mu  = s * (1.f / DIM);
        float var = s2 * (1.f / DIM) - mu * mu;
        float rs  = rsqrtf(var + 1e-5f);
#pragma unroll
        for (int i = 0; i < 6; ++i) {
            int d = lane + i * 64;
            x_ln[(size_t)n * DIM + d] = (bf16_t)((v[i] - mu) * rs * nw[d] + nb[d]);
        }
    }
}

// ---------------------------------------------------------------------------
// bf16 NT GEMM (global_load_lds + swizzle, XCD block swizzle) — R13-proven.
// EPI: 0 = fp32 C, 1 = fp32 C + resid, 2 = bf16 C.  BT = 128 or 64.
// ---------------------------------------------------------------------------
template<int EPI, int BT>
__global__ __launch_bounds__(256) void gemm_bf16(
    const bf16_t* __restrict__ A, const bf16_t* __restrict__ Bw,
    void* __restrict__ Cp, const float* __restrict__ resid,
    int M, int Nout, int K)
{
    constexpr int FRG = BT / 32;
    constexpr int WT  = BT / 2;
    __shared__ bf16_t As[BT * 64];
    __shared__ bf16_t Bs[BT * 64];
    const int tid = threadIdx.x;

    const int bid = blockIdx.y * gridDim.x + blockIdx.x;
    const int nwg = gridDim.x * gridDim.y;
    const int qq = nwg >> 3, rr8 = nwg & 7;
    const int xcd = bid & 7, loc = bid >> 3;
    const int swz = (xcd < rr8 ? xcd * (qq + 1) : rr8 * (qq + 1) + (xcd - rr8) * qq) + loc;
    const int bm = swz / gridDim.x, bn = swz % gridDim.x;

    const int wave = tid >> 6, lane = tid & 63;
    const int wr   = wave >> 1, wc = wave & 1;
    const int fr   = lane & 15, g = lane >> 4;

    f32x4 acc[FRG][FRG];
#pragma unroll
    for (int i = 0; i < FRG; ++i)
#pragma unroll
        for (int j = 0; j < FRG; ++j) acc[i][j] = (f32x4){0.f, 0.f, 0.f, 0.f};

    const bf16_t* Ab = A  + (size_t)bm * BT * K;
    const bf16_t* Bb = Bw + (size_t)bn * BT * K;

    for (int kt = 0; kt < K; kt += 64) {
        __syncthreads();
#pragma unroll
        for (int it = 0; it < BT / 32; ++it) {
            int chunk = it * 256 + tid;
            int row = chunk >> 3, c8 = chunk & 7;
            int sc8 = c8 ^ (row & 7);
            gload16(Ab + (size_t)row * K + kt + sc8 * 8, As + chunk * 8);
            gload16(Bb + (size_t)row * K + kt + sc8 * 8, Bs + chunk * 8);
        }
        __syncthreads();
#pragma unroll
        for (int kk = 0; kk < 2; ++kk) {
            bf16x8 af[FRG], bfr[FRG];
#pragma unroll
            for (int mi = 0; mi < FRG; ++mi) {
                int row = wr * WT + mi * 16 + fr;
                int c = (kk * 4 + g) ^ (row & 7);
                af[mi] = *(const bf16x8*)(As + row * 64 + c * 8);
            }
#pragma unroll
            for (int ni = 0; ni < FRG; ++ni) {
                int row = wc * WT + ni * 16 + fr;
                int c = (kk * 4 + g) ^ (row & 7);
                bfr[ni] = *(const bf16x8*)(Bs + row * 64 + c * 8);
            }
#pragma unroll
            for (int mi = 0; mi < FRG; ++mi)
#pragma unroll
                for (int ni = 0; ni < FRG; ++ni)
                    acc[mi][ni] = __builtin_amdgcn_mfma_f32_16x16x32_bf16(
                        af[mi], bfr[ni], acc[mi][ni], 0, 0, 0);
        }
    }

    const int r0 = g << 2;
#pragma unroll
    for (int mi = 0; mi < FRG; ++mi) {
#pragma unroll
        for (int ni = 0; ni < FRG; ++ni) {
#pragma unroll
            for (int e = 0; e < 4; ++e) {
                int row = bm * BT + wr * WT + mi * 16 + r0 + e;
                int col = bn * BT + wc * WT + ni * 16 + fr;
                float v = acc[mi][ni][e];
                if (EPI == 2) {
                    ((bf16_t*)Cp)[(size_t)row * Nout + col] = (bf16_t)v;
                } else {
                    if (EPI == 1) v += resid[(size_t)row * Nout + col];
                    ((float*)Cp)[(size_t)row * Nout + col] = v;
                }
            }
        }
    }
}

// ---------------------------------------------------------------------------
// Pre-rotate the k-half of the kv map in place. One thread per (row, head).
// ---------------------------------------------------------------------------
__global__ __launch_bounds__(256) void rope_k_kernel(
    bf16_t* __restrict__ kvm, const float2* __restrict__ tabS,
    const float2* __restrict__ tabL, int Mkv)
{
    int t = blockIdx.x * 256 + threadIdx.x;
    if (t >= Mkv * NHEAD) return;
    int row = t >> 3, h = t & 7;

    int rr = row % TOTAL;
    int l, i, j;
    if (rr < 4096)      { l = 0; i = rr >> 6;               j = rr & 63; }
    else if (rr < 5120) { l = 1; int u = rr - 4096; i = u >> 5; j = u & 31; }
    else if (rr < 5376) { l = 2; int u = rr - 5120; i = u >> 4; j = u & 15; }
    else                { l = 3; int u = rr - 5376; i = u >> 3; j = u & 7;  }

    bf16_t* base = kvm + (size_t)row * (2 * DIM) + h * HDIM;
    bf16x8 xa[3], xb[3];
#pragma unroll
    for (int k = 0; k < 3; ++k) {
        xa[k] = *(const bf16x8*)(base + 8 * k);
        xb[k] = *(const bf16x8*)(base + HALFD + 8 * k);
    }
#pragma unroll
    for (int d = 0; d < HALFD; ++d) {
        float2 cs = (d < 8) ? tabS[i * 8 + d]
                  : (d < 16) ? tabS[j * 8 + (d - 8)]
                             : tabL[l * 8 + (d - 16)];
        float x1 = (float)xa[d >> 3][d & 7];
        float x2 = (float)xb[d >> 3][d & 7];
        xa[d >> 3][d & 7] = (bf16_t)(x1 * cs.x - x2 * cs.y);
        xb[d >> 3][d & 7] = (bf16_t)(x1 * cs.y + x2 * cs.x);
    }
#pragma unroll
    for (int k = 0; k < 3; ++k) {
        *(bf16x8*)(base + 8 * k)         = xa[k];
        *(bf16x8*)(base + HALFD + 8 * k) = xb[k];
    }
}

// ---------------------------------------------------------------------------
// Attention partials: grid 2048 = half*1024 + q. Block handles all 8 heads
// for 98 keys (half 0: levels 0-1, half 1: levels 2-3). Key rows are
// EXCLUSIVE to one block -> no fetch duplication (unlike head-split).
// Writes per-half online-softmax partials: pm (max), ps (sum e), po (sum e*v).
// ---------------------------------------------------------------------------
__global__ __launch_bounds__(256) void attn_part_kernel(
    const float* __restrict__ qproj,   // (N,384) pre-RoPE fp32
    const int*   __restrict__ pos,     // (N,4) b,i,j,l
    const bf16_t* __restrict__ kvm,    // (B*total, 768) bf16, k pre-rotated
    const float2* __restrict__ tabS, const float2* __restrict__ tabL,
    float* __restrict__ pm, float* __restrict__ ps, float* __restrict__ po)
{
    __shared__ float qs[DIM];
    __shared__ float sc[NHEAD * HKEY];
    __shared__ int   flatL[HKEY], validL[HKEY];
    __shared__ float ptv[5][DIM];

    const int bid = blockIdx.x, tid = threadIdx.x;
    const int q    = bid & 1023;                   // XCD = q & 7 for both halves
    const int half = bid >> 10;
    const int n = ((q & 7) << 7) | (q >> 3);       // XCD-chunked remap
    const int b  = pos[n * 4 + 0];
    const int qi = pos[n * 4 + 1];
    const int qj = pos[n * 4 + 2];
    const int ql = pos[n * 4 + 3];

    // q RoPE -> qs (threads 0..191)
    if (tid < NHEAD * HALFD) {
        int h = tid / HALFD, d = tid - (tid / HALFD) * HALFD;
        float2 cs = (d < 8) ? tabS[qi * 8 + d]
                  : (d < 16) ? tabS[qj * 8 + (d - 8)]
                             : tabL[ql * 8 + (d - 16)];
        float x1 = qproj[(size_t)n * DIM + h * HDIM + d];
        float x2 = qproj[(size_t)n * DIM + h * HDIM + HALFD + d];
        qs[h * HDIM + d]         = x1 * cs.x - x2 * cs.y;
        qs[h * HDIM + HALFD + d] = x1 * cs.y + x2 * cs.x;
    }

    // geometry for this half's 98 keys, pure integer
    if (tid < HKEY) {
        int kg = half * HKEY + tid;
        int l = kg / 49, rem = kg - l * 49;
        int a = rem / 7, bb2 = rem - a * 7;
        int Hl = 64 >> l;
        int off = (l == 0) ? 0 : (l == 1) ? 4096 : (l == 2) ? 5120 : 5376;
        int e = ql - l;
        int ti = 2 * qi + 1, tj = 2 * qj + 1;
        int ci = (e >= 1) ? (ti << (e - 1)) : (ti >> (1 - e));
        int cj = (e >= 1) ? (tj << (e - 1)) : (tj >> (1 - e));
        int ii = ci + a - 3, jj = cj + bb2 - 3;
        int valid = (ii >= 0) && (ii < Hl) && (jj >= 0) && (jj < Hl);
        ii = min(max(ii, 0), Hl - 1); jj = min(max(jj, 0), Hl - 1);
        flatL[tid]  = off + ii * Hl + jj;
        validL[tid] = valid;
    }
    __syncthreads();

    const size_t bbase = (size_t)b * TOTAL;

    // scores: 8 heads x 98 keys (784 tasks)
    for (int idx = tid; idx < NHEAD * HKEY; idx += 256) {
        int h = idx / HKEY, kk = idx - h * HKEY;
        const bf16_t* krow = kvm + (bbase + (size_t)flatL[kk]) * (2 * DIM) + h * HDIM;
        bf16x8 kv[6];
#pragma unroll
        for (int i = 0; i < 6; ++i) kv[i] = *(const bf16x8*)(krow + i * 8);
        float dot = 0.f;
#pragma unroll
        for (int i = 0; i < 6; ++i)
#pragma unroll
            for (int e = 0; e < 8; ++e)
                dot += (float)kv[i][e] * qs[h * HDIM + i * 8 + e];
        float score = dot * 0.14433756729740643f;  // 1/sqrt(48)
        if (!validL[kk]) score = -1e9f;
        sc[h * HKEY + kk] = score;
    }
    __syncthreads();

    // partial softmax: head h by threads [h*32, h*32+32); e-values kept
    // UNNORMALIZED in sc; (mx, sum) written to pm/ps.
    {
        int h = tid >> 5, lg = tid & 31;
        float mx = -1e30f;
        for (int j = lg; j < HKEY; j += 32) mx = fmaxf(mx, sc[h * HKEY + j]);
#pragma unroll
        for (int m = 16; m; m >>= 1) mx = fmaxf(mx, __shfl_xor(mx, m));
        float sum = 0.f;
        for (int j = lg; j < HKEY; j += 32) {
            float e = __expf(sc[h * HKEY + j] - mx);
            sc[h * HKEY + j] = e; sum += e;
        }
#pragma unroll
        for (int m = 16; m; m >>= 1) sum += __shfl_xor(sum, m);
        if (lg == 0) {
            pm[((size_t)n * 2 + half) * NHEAD + h] = mx;
            ps[((size_t)n * 2 + half) * NHEAD + h] = sum;
        }
    }
    __syncthreads();

    // V accumulation (unnormalized): 240 threads = 5 key-groups x 48 octets
    if (tid < 240) {
        int g5 = tid / 48, o = tid - (tid / 48) * 48;
        int h = o / 6;
        float a[8];
#pragma unroll
        for (int e = 0; e < 8; ++e) a[e] = 0.f;
        const float* sch = sc + h * HKEY;
#pragma unroll 4
        for (int kk = g5; kk < HKEY; kk += 5) {
            float w = sch[kk];
            bf16x8 vv = *(const bf16x8*)(kvm + (bbase + (size_t)flatL[kk]) * (2 * DIM)
                                         + DIM + 8 * o);
#pragma unroll
            for (int e = 0; e < 8; ++e) a[e] += w * (float)vv[e];
        }
        float4 lo = { a[0], a[1], a[2], a[3] };
        float4 hi = { a[4], a[5], a[6], a[7] };
        *(float4*)(&ptv[g5][8 * o])     = lo;
        *(float4*)(&ptv[g5][8 * o + 4]) = hi;
    }
    __syncthreads();

    // reduce over key-groups -> po (fp32)
    if (tid < 192) {
        int d0 = 2 * tid;
        float s0 = 0.f, s1 = 0.f;
#pragma unroll
        for (int g5 = 0; g5 < 5; ++g5) {
            s0 += ptv[g5][d0];
            s1 += ptv[g5][d0 + 1];
        }
        float2 o2 = { s0, s1 };
        *(float2*)(po + ((size_t)n * 2 + half) * DIM + d0) = o2;
    }
}

// ---------------------------------------------------------------------------
// Combine the two key-half partials into the final attention output.
// ---------------------------------------------------------------------------
__global__ __launch_bounds__(192) void attn_comb_kernel(
    const float* __restrict__ pm, const float* __restrict__ ps,
    const float* __restrict__ po, bf16_t* __restrict__ attn_out)
{
    const int n = blockIdx.x, tid = threadIdx.x;
    const int h = tid / 24;
    float mA = pm[((size_t)n * 2 + 0) * NHEAD + h];
    float mB = pm[((size_t)n * 2 + 1) * NHEAD + h];
    float sA = ps[((size_t)n * 2 + 0) * NHEAD + h];
    float sB = ps[((size_t)n * 2 + 1) * NHEAD + h];
    float m  = fmaxf(mA, mB);
    float eA = __expf(mA - m), eB = __expf(mB - m);
    float inv = 1.f / (sA * eA + sB * eB);
    int d0 = 2 * tid;
    float2 oA = *(const float2*)(po + ((size_t)n * 2 + 0) * DIM + d0);
    float2 oB = *(const float2*)(po + ((size_t)n * 2 + 1) * DIM + d0);
    float a0 = (oA.x * eA + oB.x * eB) * inv;
    float a1 = (oA.y * eA + oB.y * eB) * inv;
    bf16x2 o = { (bf16_t)a0, (bf16_t)a1 };
    *(bf16x2*)(attn_out + (size_t)n * DIM + d0) = o;
}

// ---------------------------------------------------------------------------
extern "C" void kernel_launch(void* const* d_in, const int* in_sizes, int n_in,
                              void* d_out, int out_size, void* d_ws, size_t ws_size,
                              hipStream_t stream)
{
    const float* query  = (const float*)d_in[0];
    const int*   pos    = (const int*)d_in[1];
    const float* fmaps  = (const float*)d_in[3];
    const float* nw     = (const float*)d_in[5];
    const float* nb     = (const float*)d_in[6];
    const float* wq     = (const float*)d_in[7];
    const float* wkv    = (const float*)d_in[8];
    const float* wout   = (const float*)d_in[9];
    float* out = (float*)d_out;

    const int Mkv = in_sizes[3] / DIM;  // B*total = 21760

    char* w = (char*)d_ws;
    auto alloc = [&](size_t bytes) { char* p = w; w += (bytes + 255) & ~(size_t)255; return p; };
    bf16_t* x_ln    = (bf16_t*)alloc((size_t)NQ * DIM * 2);
    float*  qproj   = (float*) alloc((size_t)NQ * DIM * 4);
    bf16_t* attn_o  = (bf16_t*)alloc((size_t)NQ * DIM * 2);
    bf16_t* kvm     = (bf16_t*)alloc((size_t)Mkv * 2 * DIM * 2);
    bf16_t* fm_bf   = (bf16_t*)alloc((size_t)Mkv * DIM * 2);
    bf16_t* wq_bf   = (bf16_t*)alloc((size_t)DIM * DIM * 2);
    bf16_t* wkv_bf  = (bf16_t*)alloc((size_t)2 * DIM * DIM * 2);
    bf16_t* wout_bf = (bf16_t*)alloc((size_t)DIM * DIM * 2);
    float2* tabS    = (float2*)alloc(512 * 8);
    float2* tabL    = (float2*)alloc(32 * 8);
    float*  pm      = (float*)alloc((size_t)NQ * 2 * NHEAD * 4);
    float*  ps      = (float*)alloc((size_t)NQ * 2 * NHEAD * 4);
    float*  po      = (float*)alloc((size_t)NQ * 2 * DIM * 4);

    const int nfm = Mkv * DIM / 4 / 256;   // fmaps cvt blocks (8160)
    prep_kernel<<<nfm + 577 + 256, 256, 0, stream>>>(
        fmaps, fm_bf, nfm, wq, wkv, wout, wq_bf, wkv_bf, wout_bf, tabS, tabL,
        query, nw, nb, x_ln);
    gemm_bf16<0, 64><<<dim3(DIM / 64, NQ / 64), 256, 0, stream>>>(
        x_ln, wq_bf, (void*)qproj, nullptr, NQ, DIM, DIM);
    gemm_bf16<2, 128><<<dim3((2 * DIM) / 128, Mkv / 128), 256, 0, stream>>>(
        fm_bf, wkv_bf, (void*)kvm, nullptr, Mkv, 2 * DIM, DIM);
    rope_k_kernel<<<(Mkv * NHEAD + 255) / 256, 256, 0, stream>>>(kvm, tabS, tabL, Mkv);
    attn_part_kernel<<<2 * NQ, 256, 0, stream>>>(qproj, pos, kvm, tabS, tabL, pm, ps, po);
    attn_comb_kernel<<<NQ, 192, 0, stream>>>(pm, ps, po, attn_o);
    gemm_bf16<1, 64><<<dim3(DIM / 64, NQ / 64), 256, 0, stream>>>(
        attn_o, wout_bf, (void*)out, query, NQ, DIM, DIM);
}

// Round 17
// 91.468 us; speedup vs baseline: 1.0435x; 1.0435x over previous
//
#include <hip/hip_runtime.h>
#include <hip/hip_bf16.h>

typedef __bf16 bf16_t;
typedef __attribute__((ext_vector_type(4))) float f32x4;
typedef __attribute__((ext_vector_type(8))) __bf16 bf16x8;
typedef __attribute__((ext_vector_type(4))) __bf16 bf16x4;
typedef __attribute__((ext_vector_type(2))) __bf16 bf16x2;

#define NQ    1024
#define DIM   384
#define NHEAD 8
#define HDIM  48
#define HALFD 24
#define NKEY  196
#define TOTAL 5440   // 64*64 + 32*32 + 16*16 + 8*8

typedef __attribute__((address_space(1))) void gas_void;
typedef __attribute__((address_space(3))) void las_void;
__device__ __forceinline__ void gload16(const void* g, void* l) {
    __builtin_amdgcn_global_load_lds((gas_void*)g, (las_void*)l, 16, 0, 0);
}

// ---------------------------------------------------------------------------
// prep: fmaps fp32->bf16 (blocks [0,nfm)), weights (nfm..nfm+575),
// sincos tables (nfm+576), fused LayerNorm (nfm+577.., 4 rows/blk).
// ---------------------------------------------------------------------------
__global__ __launch_bounds__(256) void prep_kernel(
    const float* __restrict__ fmaps, bf16_t* __restrict__ fm_bf, int nfm,
    const float* __restrict__ wq, const float* __restrict__ wkv,
    const float* __restrict__ wout, bf16_t* __restrict__ wq_bf,
    bf16_t* __restrict__ wkv_bf, bf16_t* __restrict__ wout_bf,
    float2* __restrict__ tabS, float2* __restrict__ tabL,
    const float* __restrict__ query, const float* __restrict__ nw,
    const float* __restrict__ nb, bf16_t* __restrict__ x_ln)
{
    int bid = blockIdx.x;
    if (bid < nfm) {
        int i = bid * 256 + threadIdx.x;
        float4 v = ((const float4*)fmaps)[i];
        bf16x4 o = { (bf16_t)v.x, (bf16_t)v.y, (bf16_t)v.z, (bf16_t)v.w };
        ((bf16x4*)fm_bf)[i] = o;
        return;
    }
    int wb = bid - nfm;
    if (wb < 576) {
        int i = wb * 256 + threadIdx.x;
        const float* src; bf16_t* dst; int off;
        if (i < 36864)       { src = wq;   dst = wq_bf;   off = i; }
        else if (i < 110592) { src = wkv;  dst = wkv_bf;  off = i - 36864; }
        else                 { src = wout; dst = wout_bf; off = i - 110592; }
        float4 v = ((const float4*)src)[off];
        bf16x4 o = { (bf16_t)v.x, (bf16_t)v.y, (bf16_t)v.z, (bf16_t)v.w };
        ((bf16x4*)dst)[off] = o;
        return;
    }
    if (wb == 576) {
        int t = threadIdx.x;
        if (t < 512) {
            int i = t >> 3, f = t & 7;
            float fr = powf(10.f, -(float)f / 8.f);
            float s, c; sincosf((float)i * fr, &s, &c);
            tabS[t] = make_float2(c, s);
        } else if (t < 544) {
            int u = t - 512; int l = u >> 3, f = u & 7;
            float fr = powf(10.f, (float)f / 8.f);
            float s, c; sincosf((float)l * fr, &s, &c);
            tabL[u] = make_float2(c, s);
        }
        return;
    }
    // LayerNorm: 4 rows per block, one wave per row
    {
        int n = (wb - 577) * 4 + (threadIdx.x >> 6);
        int lane = threadIdx.x & 63;
        const float* row = query + (size_t)n * DIM;
        float v[6], s = 0.f, s2 = 0.f;
#pragma unroll
        for (int i = 0; i < 6; ++i) {
            v[i] = row[lane + i * 64];
            s += v[i]; s2 += v[i] * v[i];
        }
#pragma unroll
        for (int m = 32; m; m >>= 1) { s += __shfl_xor(s, m); s2 += __shfl_xor(s2, m); }
        float mu  = s * (1.f / DIM);
        float var = s2 * (1.f / DIM) - mu * mu;
        float rs  = rsqrtf(var + 1e-5f);
#pragma unroll
        for (int i = 0; i < 6; ++i) {
            int d = lane + i * 64;
            x_ln[(size_t)n * DIM + d] = (bf16_t)((v[i] - mu) * rs * nw[d] + nb[d]);
        }
    }
}

// ---------------------------------------------------------------------------
// bf16 NT GEMM (global_load_lds + swizzle, XCD block swizzle) — R13-proven.
// EPI: 0 = fp32 C, 1 = fp32 C + resid, 2 = bf16 C.  BT = 128 or 64.
// ---------------------------------------------------------------------------
template<int EPI, int BT>
__global__ __launch_bounds__(256) void gemm_bf16(
    const bf16_t* __restrict__ A, const bf16_t* __restrict__ Bw,
    void* __restrict__ Cp, const float* __restrict__ resid,
    int M, int Nout, int K)
{
    constexpr int FRG = BT / 32;
    constexpr int WT  = BT / 2;
    __shared__ bf16_t As[BT * 64];
    __shared__ bf16_t Bs[BT * 64];
    const int tid = threadIdx.x;

    const int bid = blockIdx.y * gridDim.x + blockIdx.x;
    const int nwg = gridDim.x * gridDim.y;
    const int qq = nwg >> 3, rr8 = nwg & 7;
    const int xcd = bid & 7, loc = bid >> 3;
    const int swz = (xcd < rr8 ? xcd * (qq + 1) : rr8 * (qq + 1) + (xcd - rr8) * qq) + loc;
    const int bm = swz / gridDim.x, bn = swz % gridDim.x;

    const int wave = tid >> 6, lane = tid & 63;
    const int wr   = wave >> 1, wc = wave & 1;
    const int fr   = lane & 15, g = lane >> 4;

    f32x4 acc[FRG][FRG];
#pragma unroll
    for (int i = 0; i < FRG; ++i)
#pragma unroll
        for (int j = 0; j < FRG; ++j) acc[i][j] = (f32x4){0.f, 0.f, 0.f, 0.f};

    const bf16_t* Ab = A  + (size_t)bm * BT * K;
    const bf16_t* Bb = Bw + (size_t)bn * BT * K;

    for (int kt = 0; kt < K; kt += 64) {
        __syncthreads();
#pragma unroll
        for (int it = 0; it < BT / 32; ++it) {
            int chunk = it * 256 + tid;
            int row = chunk >> 3, c8 = chunk & 7;
            int sc8 = c8 ^ (row & 7);
            gload16(Ab + (size_t)row * K + kt + sc8 * 8, As + chunk * 8);
            gload16(Bb + (size_t)row * K + kt + sc8 * 8, Bs + chunk * 8);
        }
        __syncthreads();
#pragma unroll
        for (int kk = 0; kk < 2; ++kk) {
            bf16x8 af[FRG], bfr[FRG];
#pragma unroll
            for (int mi = 0; mi < FRG; ++mi) {
                int row = wr * WT + mi * 16 + fr;
                int c = (kk * 4 + g) ^ (row & 7);
                af[mi] = *(const bf16x8*)(As + row * 64 + c * 8);
            }
#pragma unroll
            for (int ni = 0; ni < FRG; ++ni) {
                int row = wc * WT + ni * 16 + fr;
                int c = (kk * 4 + g) ^ (row & 7);
                bfr[ni] = *(const bf16x8*)(Bs + row * 64 + c * 8);
            }
#pragma unroll
            for (int mi = 0; mi < FRG; ++mi)
#pragma unroll
                for (int ni = 0; ni < FRG; ++ni)
                    acc[mi][ni] = __builtin_amdgcn_mfma_f32_16x16x32_bf16(
                        af[mi], bfr[ni], acc[mi][ni], 0, 0, 0);
        }
    }

    const int r0 = g << 2;
#pragma unroll
    for (int mi = 0; mi < FRG; ++mi) {
#pragma unroll
        for (int ni = 0; ni < FRG; ++ni) {
#pragma unroll
            for (int e = 0; e < 4; ++e) {
                int row = bm * BT + wr * WT + mi * 16 + r0 + e;
                int col = bn * BT + wc * WT + ni * 16 + fr;
                float v = acc[mi][ni][e];
                if (EPI == 2) {
                    ((bf16_t*)Cp)[(size_t)row * Nout + col] = (bf16_t)v;
                } else {
                    if (EPI == 1) v += resid[(size_t)row * Nout + col];
                    ((float*)Cp)[(size_t)row * Nout + col] = v;
                }
            }
        }
    }
}

// ---------------------------------------------------------------------------
// Pre-rotate the k-half of the kv map in place. One thread per (row, head).
// ---------------------------------------------------------------------------
__global__ __launch_bounds__(256) void rope_k_kernel(
    bf16_t* __restrict__ kvm, const float2* __restrict__ tabS,
    const float2* __restrict__ tabL, int Mkv)
{
    int t = blockIdx.x * 256 + threadIdx.x;
    if (t >= Mkv * NHEAD) return;
    int row = t >> 3, h = t & 7;

    int rr = row % TOTAL;
    int l, i, j;
    if (rr < 4096)      { l = 0; i = rr >> 6;               j = rr & 63; }
    else if (rr < 5120) { l = 1; int u = rr - 4096; i = u >> 5; j = u & 31; }
    else if (rr < 5376) { l = 2; int u = rr - 5120; i = u >> 4; j = u & 15; }
    else                { l = 3; int u = rr - 5376; i = u >> 3; j = u & 7;  }

    bf16_t* base = kvm + (size_t)row * (2 * DIM) + h * HDIM;
    bf16x8 xa[3], xb[3];
#pragma unroll
    for (int k = 0; k < 3; ++k) {
        xa[k] = *(const bf16x8*)(base + 8 * k);
        xb[k] = *(const bf16x8*)(base + HALFD + 8 * k);
    }
#pragma unroll
    for (int d = 0; d < HALFD; ++d) {
        float2 cs = (d < 8) ? tabS[i * 8 + d]
                  : (d < 16) ? tabS[j * 8 + (d - 8)]
                             : tabL[l * 8 + (d - 16)];
        float x1 = (float)xa[d >> 3][d & 7];
        float x2 = (float)xb[d >> 3][d & 7];
        xa[d >> 3][d & 7] = (bf16_t)(x1 * cs.x - x2 * cs.y);
        xb[d >> 3][d & 7] = (bf16_t)(x1 * cs.y + x2 * cs.x);
    }
#pragma unroll
    for (int k = 0; k < 3; ++k) {
        *(bf16x8*)(base + 8 * k)         = xa[k];
        *(bf16x8*)(base + HALFD + 8 * k) = xb[k];
    }
}

// ---------------------------------------------------------------------------
// Attention: one block (256 threads) per query — R13-proven (best measured).
// XCD-chunked query remap; strided score loop; 32-lane softmax; 16B V phase.
// ---------------------------------------------------------------------------
__global__ __launch_bounds__(256) void attn_kernel(
    const float* __restrict__ qproj,   // (N,384) pre-RoPE fp32
    const int*   __restrict__ pos,     // (N,4) b,i,j,l
    const bf16_t* __restrict__ kvm,    // (B*total, 768) bf16, k pre-rotated
    const float2* __restrict__ tabS, const float2* __restrict__ tabL,
    bf16_t* __restrict__ attn_out)     // (N,384) bf16
{
    __shared__ float qs[DIM];
    __shared__ float sc[NHEAD * NKEY];
    __shared__ int   flatL[NKEY], validL[NKEY];
    __shared__ float ptv[5][DIM];

    const int bid = blockIdx.x, tid = threadIdx.x;
    const int n = ((bid & 7) << 7) | (bid >> 3);   // XCD-chunked remap
    const int b  = pos[n * 4 + 0];
    const int qi = pos[n * 4 + 1];
    const int qj = pos[n * 4 + 2];
    const int ql = pos[n * 4 + 3];

    // q RoPE -> qs (threads 0..191)
    if (tid < NHEAD * HALFD) {
        int h = tid / HALFD, d = tid - (tid / HALFD) * HALFD;
        float2 cs = (d < 8) ? tabS[qi * 8 + d]
                  : (d < 16) ? tabS[qj * 8 + (d - 8)]
                             : tabL[ql * 8 + (d - 16)];
        float x1 = qproj[(size_t)n * DIM + h * HDIM + d];
        float x2 = qproj[(size_t)n * DIM + h * HDIM + HALFD + d];
        qs[h * HDIM + d]         = x1 * cs.x - x2 * cs.y;
        qs[h * HDIM + HALFD + d] = x1 * cs.y + x2 * cs.x;
    }

    // per-key geometry, pure integer: center = floor((q+0.5)*2^(ql-l))
    if (tid < NKEY) {
        int kk = tid;
        int l = kk / 49, rem = kk - l * 49;
        int a = rem / 7, bb2 = rem - a * 7;
        int Hl = 64 >> l;
        int off = (l == 0) ? 0 : (l == 1) ? 4096 : (l == 2) ? 5120 : 5376;
        int e = ql - l;
        int ti = 2 * qi + 1, tj = 2 * qj + 1;
        int ci = (e >= 1) ? (ti << (e - 1)) : (ti >> (1 - e));
        int cj = (e >= 1) ? (tj << (e - 1)) : (tj >> (1 - e));
        int ii = ci + a - 3, jj = cj + bb2 - 3;
        int valid = (ii >= 0) && (ii < Hl) && (jj >= 0) && (jj < Hl);
        ii = min(max(ii, 0), Hl - 1); jj = min(max(jj, 0), Hl - 1);
        flatL[kk]  = off + ii * Hl + jj;
        validL[kk] = valid;
    }
    __syncthreads();

    const size_t bbase = (size_t)b * TOTAL;

    // scores: 8 heads x 196 keys
    for (int idx = tid; idx < NHEAD * NKEY; idx += 256) {
        int h = idx / NKEY, kk = idx - h * NKEY;
        const bf16_t* krow = kvm + (bbase + (size_t)flatL[kk]) * (2 * DIM) + h * HDIM;
        bf16x8 kv[6];
#pragma unroll
        for (int i = 0; i < 6; ++i) kv[i] = *(const bf16x8*)(krow + i * 8);
        float dot = 0.f;
#pragma unroll
        for (int i = 0; i < 6; ++i)
#pragma unroll
            for (int e = 0; e < 8; ++e)
                dot += (float)kv[i][e] * qs[h * HDIM + i * 8 + e];
        float score = dot * 0.14433756729740643f;  // 1/sqrt(48)
        if (!validL[kk]) score = -1e9f;
        sc[h * NKEY + kk] = score;
    }
    __syncthreads();

    // softmax: head h handled by threads [h*32, h*32+32)
    {
        int h = tid >> 5, lg = tid & 31;
        float mx = -1e30f;
        for (int j = lg; j < NKEY; j += 32) mx = fmaxf(mx, sc[h * NKEY + j]);
#pragma unroll
        for (int m = 16; m; m >>= 1) mx = fmaxf(mx, __shfl_xor(mx, m));
        float sum = 0.f;
        for (int j = lg; j < NKEY; j += 32) {
            float e = __expf(sc[h * NKEY + j] - mx);
            sc[h * NKEY + j] = e; sum += e;
        }
#pragma unroll
        for (int m = 16; m; m >>= 1) sum += __shfl_xor(sum, m);
        float inv = 1.f / sum;
        for (int j = lg; j < NKEY; j += 32) sc[h * NKEY + j] *= inv;
    }
    __syncthreads();

    // V accumulation: 240 threads = 5 key-groups x 48 dim-octets (16B loads)
    if (tid < 240) {
        int g5 = tid / 48, o = tid - (tid / 48) * 48;  // key-group, dim-octet
        int h = o / 6;                                  // head of this octet
        float a[8];
#pragma unroll
        for (int e = 0; e < 8; ++e) a[e] = 0.f;
        const float* sch = sc + h * NKEY;
#pragma unroll 4
        for (int kk = g5; kk < NKEY; kk += 5) {
            float w = sch[kk];
            bf16x8 vv = *(const bf16x8*)(kvm + (bbase + (size_t)flatL[kk]) * (2 * DIM)
                                         + DIM + 8 * o);
#pragma unroll
            for (int e = 0; e < 8; ++e) a[e] += w * (float)vv[e];
        }
        float4 lo = { a[0], a[1], a[2], a[3] };
        float4 hi = { a[4], a[5], a[6], a[7] };
        *(float4*)(&ptv[g5][8 * o])     = lo;
        *(float4*)(&ptv[g5][8 * o + 4]) = hi;
    }
    __syncthreads();

    // final reduce over key-groups: 192 threads x 2 dims
    if (tid < 192) {
        int d0 = 2 * tid;
        float s0 = 0.f, s1 = 0.f;
#pragma unroll
        for (int g5 = 0; g5 < 5; ++g5) {
            s0 += ptv[g5][d0];
            s1 += ptv[g5][d0 + 1];
        }
        bf16x2 o = { (bf16_t)s0, (bf16_t)s1 };
        *(bf16x2*)(attn_out + (size_t)n * DIM + d0) = o;
    }
}

// ---------------------------------------------------------------------------
extern "C" void kernel_launch(void* const* d_in, const int* in_sizes, int n_in,
                              void* d_out, int out_size, void* d_ws, size_t ws_size,
                              hipStream_t stream)
{
    const float* query  = (const float*)d_in[0];
    const int*   pos    = (const int*)d_in[1];
    const float* fmaps  = (const float*)d_in[3];
    const float* nw     = (const float*)d_in[5];
    const float* nb     = (const float*)d_in[6];
    const float* wq     = (const float*)d_in[7];
    const float* wkv    = (const float*)d_in[8];
    const float* wout   = (const float*)d_in[9];
    float* out = (float*)d_out;

    const int Mkv = in_sizes[3] / DIM;  // B*total = 21760

    char* w = (char*)d_ws;
    auto alloc = [&](size_t bytes) { char* p = w; w += (bytes + 255) & ~(size_t)255; return p; };
    bf16_t* x_ln    = (bf16_t*)alloc((size_t)NQ * DIM * 2);
    float*  qproj   = (float*) alloc((size_t)NQ * DIM * 4);
    bf16_t* attn_o  = (bf16_t*)alloc((size_t)NQ * DIM * 2);
    bf16_t* kvm     = (bf16_t*)alloc((size_t)Mkv * 2 * DIM * 2);
    bf16_t* fm_bf   = (bf16_t*)alloc((size_t)Mkv * DIM * 2);
    bf16_t* wq_bf   = (bf16_t*)alloc((size_t)DIM * DIM * 2);
    bf16_t* wkv_bf  = (bf16_t*)alloc((size_t)2 * DIM * DIM * 2);
    bf16_t* wout_bf = (bf16_t*)alloc((size_t)DIM * DIM * 2);
    float2* tabS    = (float2*)alloc(512 * 8);
    float2* tabL    = (float2*)alloc(32 * 8);

    const int nfm = Mkv * DIM / 4 / 256;   // fmaps cvt blocks (8160)
    prep_kernel<<<nfm + 577 + 256, 256, 0, stream>>>(
        fmaps, fm_bf, nfm, wq, wkv, wout, wq_bf, wkv_bf, wout_bf, tabS, tabL,
        query, nw, nb, x_ln);
    gemm_bf16<0, 64><<<dim3(DIM / 64, NQ / 64), 256, 0, stream>>>(
        x_ln, wq_bf, (void*)qproj, nullptr, NQ, DIM, DIM);
    gemm_bf16<2, 128><<<dim3((2 * DIM) / 128, Mkv / 128), 256, 0, stream>>>(
        fm_bf, wkv_bf, (void*)kvm, nullptr, Mkv, 2 * DIM, DIM);
    rope_k_kernel<<<(Mkv * NHEAD + 255) / 256, 256, 0, stream>>>(kvm, tabS, tabL, Mkv);
    attn_kernel<<<NQ, 256, 0, stream>>>(qproj, pos, kvm, tabS, tabL, attn_o);
    gemm_bf16<1, 64><<<dim3(DIM / 64, NQ / 64), 256, 0, stream>>>(
        attn_o, wout_bf, (void*)out, query, NQ, DIM, DIM);
}

// Round 18
// 86.415 us; speedup vs baseline: 1.1045x; 1.0585x over previous
//
#include <hip/hip_runtime.h>
#include <hip/hip_bf16.h>

typedef __bf16 bf16_t;
typedef __attribute__((ext_vector_type(4))) float f32x4;
typedef __attribute__((ext_vector_type(8))) __bf16 bf16x8;
typedef __attribute__((ext_vector_type(4))) __bf16 bf16x4;
typedef __attribute__((ext_vector_type(2))) __bf16 bf16x2;

#define NQ    1024
#define DIM   384
#define NHEAD 8
#define HDIM  48
#define HALFD 24
#define NKEY  196
#define TOTAL 5440   // 64*64 + 32*32 + 16*16 + 8*8

typedef __attribute__((address_space(1))) void gas_void;
typedef __attribute__((address_space(3))) void las_void;
__device__ __forceinline__ void gload16(const void* g, void* l) {
    __builtin_amdgcn_global_load_lds((gas_void*)g, (las_void*)l, 16, 0, 0);
}

// ---------------------------------------------------------------------------
// prep: fmaps fp32->bf16 (blocks [0,nfm)), weights (nfm..nfm+575),
// sincos tables (nfm+576), fused LayerNorm (nfm+577.., 4 rows/blk).
// ---------------------------------------------------------------------------
__global__ __launch_bounds__(256) void prep_kernel(
    const float* __restrict__ fmaps, bf16_t* __restrict__ fm_bf, int nfm,
    const float* __restrict__ wq, const float* __restrict__ wkv,
    const float* __restrict__ wout, bf16_t* __restrict__ wq_bf,
    bf16_t* __restrict__ wkv_bf, bf16_t* __restrict__ wout_bf,
    float2* __restrict__ tabS, float2* __restrict__ tabL,
    const float* __restrict__ query, const float* __restrict__ nw,
    const float* __restrict__ nb, bf16_t* __restrict__ x_ln)
{
    int bid = blockIdx.x;
    if (bid < nfm) {
        int i = bid * 256 + threadIdx.x;
        float4 v = ((const float4*)fmaps)[i];
        bf16x4 o = { (bf16_t)v.x, (bf16_t)v.y, (bf16_t)v.z, (bf16_t)v.w };
        ((bf16x4*)fm_bf)[i] = o;
        return;
    }
    int wb = bid - nfm;
    if (wb < 576) {
        int i = wb * 256 + threadIdx.x;
        const float* src; bf16_t* dst; int off;
        if (i < 36864)       { src = wq;   dst = wq_bf;   off = i; }
        else if (i < 110592) { src = wkv;  dst = wkv_bf;  off = i - 36864; }
        else                 { src = wout; dst = wout_bf; off = i - 110592; }
        float4 v = ((const float4*)src)[off];
        bf16x4 o = { (bf16_t)v.x, (bf16_t)v.y, (bf16_t)v.z, (bf16_t)v.w };
        ((bf16x4*)dst)[off] = o;
        return;
    }
    if (wb == 576) {
        int t = threadIdx.x;
        if (t < 512) {
            int i = t >> 3, f = t & 7;
            float fr = powf(10.f, -(float)f / 8.f);
            float s, c; sincosf((float)i * fr, &s, &c);
            tabS[t] = make_float2(c, s);
        } else if (t < 544) {
            int u = t - 512; int l = u >> 3, f = u & 7;
            float fr = powf(10.f, (float)f / 8.f);
            float s, c; sincosf((float)l * fr, &s, &c);
            tabL[u] = make_float2(c, s);
        }
        return;
    }
    // LayerNorm: 4 rows per block, one wave per row
    {
        int n = (wb - 577) * 4 + (threadIdx.x >> 6);
        int lane = threadIdx.x & 63;
        const float* row = query + (size_t)n * DIM;
        float v[6], s = 0.f, s2 = 0.f;
#pragma unroll
        for (int i = 0; i < 6; ++i) {
            v[i] = row[lane + i * 64];
            s += v[i]; s2 += v[i] * v[i];
        }
#pragma unroll
        for (int m = 32; m; m >>= 1) { s += __shfl_xor(s, m); s2 += __shfl_xor(s2, m); }
        float mu  = s * (1.f / DIM);
        float var = s2 * (1.f / DIM) - mu * mu;
        float rs  = rsqrtf(var + 1e-5f);
#pragma unroll
        for (int i = 0; i < 6; ++i) {
            int d = lane + i * 64;
            x_ln[(size_t)n * DIM + d] = (bf16_t)((v[i] - mu) * rs * nw[d] + nb[d]);
        }
    }
}

// ---------------------------------------------------------------------------
// bf16 NT GEMM body (R13-proven), parameterized by local bid/nwg so multiple
// sub-GEMMs can share one launch. EPI: 0 fp32 C, 1 +resid, 2 bf16 C.
// ---------------------------------------------------------------------------
template<int EPI, int BT>
__device__ __forceinline__ void gemm_body(
    int bid, int nwg, int gridx,
    const bf16_t* __restrict__ A, const bf16_t* __restrict__ Bw,
    void* __restrict__ Cp, const float* __restrict__ resid,
    int M, int Nout, int K, bf16_t* As, bf16_t* Bs)
{
    constexpr int FRG = BT / 32;
    constexpr int WT  = BT / 2;
    const int tid = threadIdx.x;

    const int qq = nwg >> 3, rr8 = nwg & 7;
    const int xcd = bid & 7, loc = bid >> 3;
    const int swz = (xcd < rr8 ? xcd * (qq + 1) : rr8 * (qq + 1) + (xcd - rr8) * qq) + loc;
    const int bm = swz / gridx, bn = swz % gridx;

    const int wave = tid >> 6, lane = tid & 63;
    const int wr   = wave >> 1, wc = wave & 1;
    const int fr   = lane & 15, g = lane >> 4;

    f32x4 acc[FRG][FRG];
#pragma unroll
    for (int i = 0; i < FRG; ++i)
#pragma unroll
        for (int j = 0; j < FRG; ++j) acc[i][j] = (f32x4){0.f, 0.f, 0.f, 0.f};

    const bf16_t* Ab = A  + (size_t)bm * BT * K;
    const bf16_t* Bb = Bw + (size_t)bn * BT * K;

    for (int kt = 0; kt < K; kt += 64) {
        __syncthreads();
#pragma unroll
        for (int it = 0; it < BT / 32; ++it) {
            int chunk = it * 256 + tid;
            int row = chunk >> 3, c8 = chunk & 7;
            int sc8 = c8 ^ (row & 7);
            gload16(Ab + (size_t)row * K + kt + sc8 * 8, As + chunk * 8);
            gload16(Bb + (size_t)row * K + kt + sc8 * 8, Bs + chunk * 8);
        }
        __syncthreads();
#pragma unroll
        for (int kk = 0; kk < 2; ++kk) {
            bf16x8 af[FRG], bfr[FRG];
#pragma unroll
            for (int mi = 0; mi < FRG; ++mi) {
                int row = wr * WT + mi * 16 + fr;
                int c = (kk * 4 + g) ^ (row & 7);
                af[mi] = *(const bf16x8*)(As + row * 64 + c * 8);
            }
#pragma unroll
            for (int ni = 0; ni < FRG; ++ni) {
                int row = wc * WT + ni * 16 + fr;
                int c = (kk * 4 + g) ^ (row & 7);
                bfr[ni] = *(const bf16x8*)(Bs + row * 64 + c * 8);
            }
#pragma unroll
            for (int mi = 0; mi < FRG; ++mi)
#pragma unroll
                for (int ni = 0; ni < FRG; ++ni)
                    acc[mi][ni] = __builtin_amdgcn_mfma_f32_16x16x32_bf16(
                        af[mi], bfr[ni], acc[mi][ni], 0, 0, 0);
        }
    }

    const int r0 = g << 2;
#pragma unroll
    for (int mi = 0; mi < FRG; ++mi) {
#pragma unroll
        for (int ni = 0; ni < FRG; ++ni) {
#pragma unroll
            for (int e = 0; e < 4; ++e) {
                int row = bm * BT + wr * WT + mi * 16 + r0 + e;
                int col = bn * BT + wc * WT + ni * 16 + fr;
                float v = acc[mi][ni][e];
                if (EPI == 2) {
                    ((bf16_t*)Cp)[(size_t)row * Nout + col] = (bf16_t)v;
                } else {
                    if (EPI == 1) v += resid[(size_t)row * Nout + col];
                    ((float*)Cp)[(size_t)row * Nout + col] = v;
                }
            }
        }
    }
}

// Standalone GEMM (out-projection)
template<int EPI, int BT>
__global__ __launch_bounds__(256) void gemm_bf16(
    const bf16_t* __restrict__ A, const bf16_t* __restrict__ Bw,
    void* __restrict__ Cp, const float* __restrict__ resid,
    int M, int Nout, int K)
{
    __shared__ bf16_t smem[2 * BT * 64];
    gemm_body<EPI, BT>(blockIdx.y * gridDim.x + blockIdx.x,
                       gridDim.x * gridDim.y, gridDim.x,
                       A, Bw, Cp, resid, M, Nout, K, smem, smem + BT * 64);
}

// Dual GEMM: blocks [0,n1) = kv (BT=128, bf16 C), [n1,n1+96) = qproj
// (BT=64, fp32 C). Shares one launch so qproj rides in kv's tile-wave.
__global__ __launch_bounds__(256) void gemm_dual(
    const bf16_t* __restrict__ A1, const bf16_t* __restrict__ B1,
    void* __restrict__ C1, int M1, int N1, int K1, int gx1, int n1,
    const bf16_t* __restrict__ A2, const bf16_t* __restrict__ B2,
    void* __restrict__ C2, int M2, int N2, int K2, int gx2, int n2)
{
    __shared__ bf16_t smem[2 * 128 * 64];
    int bid = blockIdx.x;
    if (bid < n1) {
        gemm_body<2, 128>(bid, n1, gx1, A1, B1, C1, nullptr, M1, N1, K1,
                          smem, smem + 128 * 64);
    } else {
        gemm_body<0, 64>(bid - n1, n2, gx2, A2, B2, C2, nullptr, M2, N2, K2,
                         smem, smem + 64 * 64);
    }
}

// ---------------------------------------------------------------------------
// Pre-rotate the k-half of the kv map in place. One thread per (row, head).
// ---------------------------------------------------------------------------
__global__ __launch_bounds__(256) void rope_k_kernel(
    bf16_t* __restrict__ kvm, const float2* __restrict__ tabS,
    const float2* __restrict__ tabL, int Mkv)
{
    int t = blockIdx.x * 256 + threadIdx.x;
    if (t >= Mkv * NHEAD) return;
    int row = t >> 3, h = t & 7;

    int rr = row % TOTAL;
    int l, i, j;
    if (rr < 4096)      { l = 0; i = rr >> 6;               j = rr & 63; }
    else if (rr < 5120) { l = 1; int u = rr - 4096; i = u >> 5; j = u & 31; }
    else if (rr < 5376) { l = 2; int u = rr - 5120; i = u >> 4; j = u & 15; }
    else                { l = 3; int u = rr - 5376; i = u >> 3; j = u & 7;  }

    bf16_t* base = kvm + (size_t)row * (2 * DIM) + h * HDIM;
    bf16x8 xa[3], xb[3];
#pragma unroll
    for (int k = 0; k < 3; ++k) {
        xa[k] = *(const bf16x8*)(base + 8 * k);
        xb[k] = *(const bf16x8*)(base + HALFD + 8 * k);
    }
#pragma unroll
    for (int d = 0; d < HALFD; ++d) {
        float2 cs = (d < 8) ? tabS[i * 8 + d]
                  : (d < 16) ? tabS[j * 8 + (d - 8)]
                             : tabL[l * 8 + (d - 16)];
        float x1 = (float)xa[d >> 3][d & 7];
        float x2 = (float)xb[d >> 3][d & 7];
        xa[d >> 3][d & 7] = (bf16_t)(x1 * cs.x - x2 * cs.y);
        xb[d >> 3][d & 7] = (bf16_t)(x1 * cs.y + x2 * cs.x);
    }
#pragma unroll
    for (int k = 0; k < 3; ++k) {
        *(bf16x8*)(base + 8 * k)         = xa[k];
        *(bf16x8*)(base + HALFD + 8 * k) = xb[k];
    }
}

// ---------------------------------------------------------------------------
// Attention: one block (256 threads) per query — R13-proven (best measured).
// XCD-chunked query remap; strided score loop; 32-lane softmax; 16B V phase.
// ---------------------------------------------------------------------------
__global__ __launch_bounds__(256) void attn_kernel(
    const float* __restrict__ qproj,   // (N,384) pre-RoPE fp32
    const int*   __restrict__ pos,     // (N,4) b,i,j,l
    const bf16_t* __restrict__ kvm,    // (B*total, 768) bf16, k pre-rotated
    const float2* __restrict__ tabS, const float2* __restrict__ tabL,
    bf16_t* __restrict__ attn_out)     // (N,384) bf16
{
    __shared__ float qs[DIM];
    __shared__ float sc[NHEAD * NKEY];
    __shared__ int   flatL[NKEY], validL[NKEY];
    __shared__ float ptv[5][DIM];

    const int bid = blockIdx.x, tid = threadIdx.x;
    const int n = ((bid & 7) << 7) | (bid >> 3);   // XCD-chunked remap
    const int b  = pos[n * 4 + 0];
    const int qi = pos[n * 4 + 1];
    const int qj = pos[n * 4 + 2];
    const int ql = pos[n * 4 + 3];

    // q RoPE -> qs (threads 0..191)
    if (tid < NHEAD * HALFD) {
        int h = tid / HALFD, d = tid - (tid / HALFD) * HALFD;
        float2 cs = (d < 8) ? tabS[qi * 8 + d]
                  : (d < 16) ? tabS[qj * 8 + (d - 8)]
                             : tabL[ql * 8 + (d - 16)];
        float x1 = qproj[(size_t)n * DIM + h * HDIM + d];
        float x2 = qproj[(size_t)n * DIM + h * HDIM + HALFD + d];
        qs[h * HDIM + d]         = x1 * cs.x - x2 * cs.y;
        qs[h * HDIM + HALFD + d] = x1 * cs.y + x2 * cs.x;
    }

    // per-key geometry, pure integer: center = floor((q+0.5)*2^(ql-l))
    if (tid < NKEY) {
        int kk = tid;
        int l = kk / 49, rem = kk - l * 49;
        int a = rem / 7, bb2 = rem - a * 7;
        int Hl = 64 >> l;
        int off = (l == 0) ? 0 : (l == 1) ? 4096 : (l == 2) ? 5120 : 5376;
        int e = ql - l;
        int ti = 2 * qi + 1, tj = 2 * qj + 1;
        int ci = (e >= 1) ? (ti << (e - 1)) : (ti >> (1 - e));
        int cj = (e >= 1) ? (tj << (e - 1)) : (tj >> (1 - e));
        int ii = ci + a - 3, jj = cj + bb2 - 3;
        int valid = (ii >= 0) && (ii < Hl) && (jj >= 0) && (jj < Hl);
        ii = min(max(ii, 0), Hl - 1); jj = min(max(jj, 0), Hl - 1);
        flatL[kk]  = off + ii * Hl + jj;
        validL[kk] = valid;
    }
    __syncthreads();

    const size_t bbase = (size_t)b * TOTAL;

    // scores: 8 heads x 196 keys
    for (int idx = tid; idx < NHEAD * NKEY; idx += 256) {
        int h = idx / NKEY, kk = idx - h * NKEY;
        const bf16_t* krow = kvm + (bbase + (size_t)flatL[kk]) * (2 * DIM) + h * HDIM;
        bf16x8 kv[6];
#pragma unroll
        for (int i = 0; i < 6; ++i) kv[i] = *(const bf16x8*)(krow + i * 8);
        float dot = 0.f;
#pragma unroll
        for (int i = 0; i < 6; ++i)
#pragma unroll
            for (int e = 0; e < 8; ++e)
                dot += (float)kv[i][e] * qs[h * HDIM + i * 8 + e];
        float score = dot * 0.14433756729740643f;  // 1/sqrt(48)
        if (!validL[kk]) score = -1e9f;
        sc[h * NKEY + kk] = score;
    }
    __syncthreads();

    // softmax: head h handled by threads [h*32, h*32+32)
    {
        int h = tid >> 5, lg = tid & 31;
        float mx = -1e30f;
        for (int j = lg; j < NKEY; j += 32) mx = fmaxf(mx, sc[h * NKEY + j]);
#pragma unroll
        for (int m = 16; m; m >>= 1) mx = fmaxf(mx, __shfl_xor(mx, m));
        float sum = 0.f;
        for (int j = lg; j < NKEY; j += 32) {
            float e = __expf(sc[h * NKEY + j] - mx);
            sc[h * NKEY + j] = e; sum += e;
        }
#pragma unroll
        for (int m = 16; m; m >>= 1) sum += __shfl_xor(sum, m);
        float inv = 1.f / sum;
        for (int j = lg; j < NKEY; j += 32) sc[h * NKEY + j] *= inv;
    }
    __syncthreads();

    // V accumulation: 240 threads = 5 key-groups x 48 dim-octets (16B loads)
    if (tid < 240) {
        int g5 = tid / 48, o = tid - (tid / 48) * 48;  // key-group, dim-octet
        int h = o / 6;                                  // head of this octet
        float a[8];
#pragma unroll
        for (int e = 0; e < 8; ++e) a[e] = 0.f;
        const float* sch = sc + h * NKEY;
#pragma unroll 4
        for (int kk = g5; kk < NKEY; kk += 5) {
            float w = sch[kk];
            bf16x8 vv = *(const bf16x8*)(kvm + (bbase + (size_t)flatL[kk]) * (2 * DIM)
                                         + DIM + 8 * o);
#pragma unroll
            for (int e = 0; e < 8; ++e) a[e] += w * (float)vv[e];
        }
        float4 lo = { a[0], a[1], a[2], a[3] };
        float4 hi = { a[4], a[5], a[6], a[7] };
        *(float4*)(&ptv[g5][8 * o])     = lo;
        *(float4*)(&ptv[g5][8 * o + 4]) = hi;
    }
    __syncthreads();

    // final reduce over key-groups: 192 threads x 2 dims
    if (tid < 192) {
        int d0 = 2 * tid;
        float s0 = 0.f, s1 = 0.f;
#pragma unroll
        for (int g5 = 0; g5 < 5; ++g5) {
            s0 += ptv[g5][d0];
            s1 += ptv[g5][d0 + 1];
        }
        bf16x2 o = { (bf16_t)s0, (bf16_t)s1 };
        *(bf16x2*)(attn_out + (size_t)n * DIM + d0) = o;
    }
}

// ---------------------------------------------------------------------------
extern "C" void kernel_launch(void* const* d_in, const int* in_sizes, int n_in,
                              void* d_out, int out_size, void* d_ws, size_t ws_size,
                              hipStream_t stream)
{
    const float* query  = (const float*)d_in[0];
    const int*   pos    = (const int*)d_in[1];
    const float* fmaps  = (const float*)d_in[3];
    const float* nw     = (const float*)d_in[5];
    const float* nb     = (const float*)d_in[6];
    const float* wq     = (const float*)d_in[7];
    const float* wkv    = (const float*)d_in[8];
    const float* wout   = (const float*)d_in[9];
    float* out = (float*)d_out;

    const int Mkv = in_sizes[3] / DIM;  // B*total = 21760

    char* w = (char*)d_ws;
    auto alloc = [&](size_t bytes) { char* p = w; w += (bytes + 255) & ~(size_t)255; return p; };
    bf16_t* x_ln    = (bf16_t*)alloc((size_t)NQ * DIM * 2);
    float*  qproj   = (float*) alloc((size_t)NQ * DIM * 4);
    bf16_t* attn_o  = (bf16_t*)alloc((size_t)NQ * DIM * 2);
    bf16_t* kvm     = (bf16_t*)alloc((size_t)Mkv * 2 * DIM * 2);
    bf16_t* fm_bf   = (bf16_t*)alloc((size_t)Mkv * DIM * 2);
    bf16_t* wq_bf   = (bf16_t*)alloc((size_t)DIM * DIM * 2);
    bf16_t* wkv_bf  = (bf16_t*)alloc((size_t)2 * DIM * DIM * 2);
    bf16_t* wout_bf = (bf16_t*)alloc((size_t)DIM * DIM * 2);
    float2* tabS    = (float2*)alloc(512 * 8);
    float2* tabL    = (float2*)alloc(32 * 8);

    const int nfm = Mkv * DIM / 4 / 256;   // fmaps cvt blocks (8160)
    prep_kernel<<<nfm + 577 + 256, 256, 0, stream>>>(
        fmaps, fm_bf, nfm, wq, wkv, wout, wq_bf, wkv_bf, wout_bf, tabS, tabL,
        query, nw, nb, x_ln);
    {
        const int n1 = (2 * DIM / 128) * (Mkv / 128);   // 6*170 = 1020 kv blocks
        const int n2 = (DIM / 64) * (NQ / 64);          // 6*16  = 96 qproj blocks
        gemm_dual<<<n1 + n2, 256, 0, stream>>>(
            fm_bf, wkv_bf, (void*)kvm, Mkv, 2 * DIM, DIM, 2 * DIM / 128, n1,
            x_ln, wq_bf, (void*)qproj, NQ, DIM, DIM, DIM / 64, n2);
    }
    rope_k_kernel<<<(Mkv * NHEAD + 255) / 256, 256, 0, stream>>>(kvm, tabS, tabL, Mkv);
    attn_kernel<<<NQ, 256, 0, stream>>>(qproj, pos, kvm, tabS, tabL, attn_o);
    gemm_bf16<1, 64><<<dim3(DIM / 64, NQ / 64), 256, 0, stream>>>(
        attn_o, wout_bf, (void*)out, query, NQ, DIM, DIM);
}

// Round 19
// 84.720 us; speedup vs baseline: 1.1266x; 1.0200x over previous
//
#include <hip/hip_runtime.h>
#include <hip/hip_bf16.h>

typedef __bf16 bf16_t;
typedef __attribute__((ext_vector_type(4))) float f32x4;
typedef __attribute__((ext_vector_type(8))) __bf16 bf16x8;
typedef __attribute__((ext_vector_type(4))) __bf16 bf16x4;
typedef __attribute__((ext_vector_type(2))) __bf16 bf16x2;

#define NQ    1024
#define DIM   384
#define NHEAD 8
#define HDIM  48
#define HALFD 24
#define NKEY  196
#define TOTAL 5440   // 64*64 + 32*32 + 16*16 + 8*8

typedef __attribute__((address_space(1))) void gas_void;
typedef __attribute__((address_space(3))) void las_void;
__device__ __forceinline__ void gload16(const void* g, void* l) {
    __builtin_amdgcn_global_load_lds((gas_void*)g, (las_void*)l, 16, 0, 0);
}

// ---------------------------------------------------------------------------
// prep: fmaps fp32->bf16 (blocks [0,nfm)), weights (nfm..nfm+575),
// sincos tables (nfm+576), fused LayerNorm (nfm+577..nfm+832, 4 rows/blk),
// spatial bucket sort of queries (block nfm+833).
// ---------------------------------------------------------------------------
__global__ __launch_bounds__(256) void prep_kernel(
    const float* __restrict__ fmaps, bf16_t* __restrict__ fm_bf, int nfm,
    const float* __restrict__ wq, const float* __restrict__ wkv,
    const float* __restrict__ wout, bf16_t* __restrict__ wq_bf,
    bf16_t* __restrict__ wkv_bf, bf16_t* __restrict__ wout_bf,
    float2* __restrict__ tabS, float2* __restrict__ tabL,
    const float* __restrict__ query, const float* __restrict__ nw,
    const float* __restrict__ nb, bf16_t* __restrict__ x_ln,
    const int* __restrict__ pos, int* __restrict__ order)
{
    int bid = blockIdx.x;
    if (bid < nfm) {
        int i = bid * 256 + threadIdx.x;
        float4 v = ((const float4*)fmaps)[i];
        bf16x4 o = { (bf16_t)v.x, (bf16_t)v.y, (bf16_t)v.z, (bf16_t)v.w };
        ((bf16x4*)fm_bf)[i] = o;
        return;
    }
    int wb = bid - nfm;
    if (wb < 576) {
        int i = wb * 256 + threadIdx.x;
        const float* src; bf16_t* dst; int off;
        if (i < 36864)       { src = wq;   dst = wq_bf;   off = i; }
        else if (i < 110592) { src = wkv;  dst = wkv_bf;  off = i - 36864; }
        else                 { src = wout; dst = wout_bf; off = i - 110592; }
        float4 v = ((const float4*)src)[off];
        bf16x4 o = { (bf16_t)v.x, (bf16_t)v.y, (bf16_t)v.z, (bf16_t)v.w };
        ((bf16x4*)dst)[off] = o;
        return;
    }
    if (wb == 576) {
        int t = threadIdx.x;
        if (t < 512) {
            int i = t >> 3, f = t & 7;
            float fr = powf(10.f, -(float)f / 8.f);
            float s, c; sincosf((float)i * fr, &s, &c);
            tabS[t] = make_float2(c, s);
        } else if (t < 544) {
            int u = t - 512; int l = u >> 3, f = u & 7;
            float fr = powf(10.f, (float)f / 8.f);
            float s, c; sincosf((float)l * fr, &s, &c);
            tabL[u] = make_float2(c, s);
        }
        return;
    }
    if (wb == 833) {
        // spatial bucket sort: bucket = (b<<4) | cell, cell = 4x4 grid of
        // normalized (level-0 scale) position. XCD x then serves a compact
        // ~half-batch region -> attn working set fits its 4MB L2.
        __shared__ int cnt[64], base_[64];
        int t = threadIdx.x;
        if (t < 64) cnt[t] = 0;
        __syncthreads();
        int mybkt[4];
#pragma unroll
        for (int k2 = 0; k2 < 4; ++k2) {
            int q = t * 4 + k2;
            int b = pos[q * 4], qi = pos[q * 4 + 1], qj = pos[q * 4 + 2], ql = pos[q * 4 + 3];
            int ni = ((2 * qi + 1) << ql) >> 1;   // [0,64)
            int nj = ((2 * qj + 1) << ql) >> 1;
            mybkt[k2] = (b << 4) | ((ni >> 4) << 2) | (nj >> 4);
            atomicAdd(&cnt[mybkt[k2]], 1);
        }
        __syncthreads();
        if (t == 0) {
            int s = 0;
            for (int i2 = 0; i2 < 64; ++i2) { base_[i2] = s; s += cnt[i2]; }
        }
        __syncthreads();
        if (t < 64) cnt[t] = 0;
        __syncthreads();
#pragma unroll
        for (int k2 = 0; k2 < 4; ++k2) {
            int q = t * 4 + k2;
            int slot = base_[mybkt[k2]] + atomicAdd(&cnt[mybkt[k2]], 1);
            order[slot] = q;
        }
        return;
    }
    // LayerNorm: 4 rows per block, one wave per row
    {
        int n = (wb - 577) * 4 + (threadIdx.x >> 6);
        int lane = threadIdx.x & 63;
        const float* row = query + (size_t)n * DIM;
        float v[6], s = 0.f, s2 = 0.f;
#pragma unroll
        for (int i = 0; i < 6; ++i) {
            v[i] = row[lane + i * 64];
            s += v[i]; s2 += v[i] * v[i];
        }
#pragma unroll
        for (int m = 32; m; m >>= 1) { s += __shfl_xor(s, m); s2 += __shfl_xor(s2, m); }
        float mu  = s * (1.f / DIM);
        float var = s2 * (1.f / DIM) - mu * mu;
        float rs  = rsqrtf(var + 1e-5f);
#pragma unroll
        for (int i = 0; i < 6; ++i) {
            int d = lane + i * 64;
            x_ln[(size_t)n * DIM + d] = (bf16_t)((v[i] - mu) * rs * nw[d] + nb[d]);
        }
    }
}

// ---------------------------------------------------------------------------
// bf16 NT GEMM body (R13-proven), parameterized by local bid/nwg so multiple
// sub-GEMMs can share one launch. EPI: 0 fp32 C, 1 +resid, 2 bf16 C.
// ---------------------------------------------------------------------------
template<int EPI, int BT>
__device__ __forceinline__ void gemm_body(
    int bid, int nwg, int gridx,
    const bf16_t* __restrict__ A, const bf16_t* __restrict__ Bw,
    void* __restrict__ Cp, const float* __restrict__ resid,
    int M, int Nout, int K, bf16_t* As, bf16_t* Bs)
{
    constexpr int FRG = BT / 32;
    constexpr int WT  = BT / 2;
    const int tid = threadIdx.x;

    const int qq = nwg >> 3, rr8 = nwg & 7;
    const int xcd = bid & 7, loc = bid >> 3;
    const int swz = (xcd < rr8 ? xcd * (qq + 1) : rr8 * (qq + 1) + (xcd - rr8) * qq) + loc;
    const int bm = swz / gridx, bn = swz % gridx;

    const int wave = tid >> 6, lane = tid & 63;
    const int wr   = wave >> 1, wc = wave & 1;
    const int fr   = lane & 15, g = lane >> 4;

    f32x4 acc[FRG][FRG];
#pragma unroll
    for (int i = 0; i < FRG; ++i)
#pragma unroll
        for (int j = 0; j < FRG; ++j) acc[i][j] = (f32x4){0.f, 0.f, 0.f, 0.f};

    const bf16_t* Ab = A  + (size_t)bm * BT * K;
    const bf16_t* Bb = Bw + (size_t)bn * BT * K;

    for (int kt = 0; kt < K; kt += 64) {
        __syncthreads();
#pragma unroll
        for (int it = 0; it < BT / 32; ++it) {
            int chunk = it * 256 + tid;
            int row = chunk >> 3, c8 = chunk & 7;
            int sc8 = c8 ^ (row & 7);
            gload16(Ab + (size_t)row * K + kt + sc8 * 8, As + chunk * 8);
            gload16(Bb + (size_t)row * K + kt + sc8 * 8, Bs + chunk * 8);
        }
        __syncthreads();
#pragma unroll
        for (int kk = 0; kk < 2; ++kk) {
            bf16x8 af[FRG], bfr[FRG];
#pragma unroll
            for (int mi = 0; mi < FRG; ++mi) {
                int row = wr * WT + mi * 16 + fr;
                int c = (kk * 4 + g) ^ (row & 7);
                af[mi] = *(const bf16x8*)(As + row * 64 + c * 8);
            }
#pragma unroll
            for (int ni = 0; ni < FRG; ++ni) {
                int row = wc * WT + ni * 16 + fr;
                int c = (kk * 4 + g) ^ (row & 7);
                bfr[ni] = *(const bf16x8*)(Bs + row * 64 + c * 8);
            }
#pragma unroll
            for (int mi = 0; mi < FRG; ++mi)
#pragma unroll
                for (int ni = 0; ni < FRG; ++ni)
                    acc[mi][ni] = __builtin_amdgcn_mfma_f32_16x16x32_bf16(
                        af[mi], bfr[ni], acc[mi][ni], 0, 0, 0);
        }
    }

    const int r0 = g << 2;
#pragma unroll
    for (int mi = 0; mi < FRG; ++mi) {
#pragma unroll
        for (int ni = 0; ni < FRG; ++ni) {
#pragma unroll
            for (int e = 0; e < 4; ++e) {
                int row = bm * BT + wr * WT + mi * 16 + r0 + e;
                int col = bn * BT + wc * WT + ni * 16 + fr;
                float v = acc[mi][ni][e];
                if (EPI == 2) {
                    ((bf16_t*)Cp)[(size_t)row * Nout + col] = (bf16_t)v;
                } else {
                    if (EPI == 1) v += resid[(size_t)row * Nout + col];
                    ((float*)Cp)[(size_t)row * Nout + col] = v;
                }
            }
        }
    }
}

// Standalone GEMM (out-projection)
template<int EPI, int BT>
__global__ __launch_bounds__(256) void gemm_bf16(
    const bf16_t* __restrict__ A, const bf16_t* __restrict__ Bw,
    void* __restrict__ Cp, const float* __restrict__ resid,
    int M, int Nout, int K)
{
    __shared__ bf16_t smem[2 * BT * 64];
    gemm_body<EPI, BT>(blockIdx.y * gridDim.x + blockIdx.x,
                       gridDim.x * gridDim.y, gridDim.x,
                       A, Bw, Cp, resid, M, Nout, K, smem, smem + BT * 64);
}

// Dual GEMM: blocks [0,n1) = kv (BT=128, bf16 C), [n1,n1+96) = qproj
// (BT=64, fp32 C). Shares one launch so qproj rides in kv's tile-wave.
__global__ __launch_bounds__(256) void gemm_dual(
    const bf16_t* __restrict__ A1, const bf16_t* __restrict__ B1,
    void* __restrict__ C1, int M1, int N1, int K1, int gx1, int n1,
    const bf16_t* __restrict__ A2, const bf16_t* __restrict__ B2,
    void* __restrict__ C2, int M2, int N2, int K2, int gx2, int n2)
{
    __shared__ bf16_t smem[2 * 128 * 64];
    int bid = blockIdx.x;
    if (bid < n1) {
        gemm_body<2, 128>(bid, n1, gx1, A1, B1, C1, nullptr, M1, N1, K1,
                          smem, smem + 128 * 64);
    } else {
        gemm_body<0, 64>(bid - n1, n2, gx2, A2, B2, C2, nullptr, M2, N2, K2,
                         smem, smem + 64 * 64);
    }
}

// ---------------------------------------------------------------------------
// Pre-rotate the k-half of the kv map in place. One thread per (row, head).
// ---------------------------------------------------------------------------
__global__ __launch_bounds__(256) void rope_k_kernel(
    bf16_t* __restrict__ kvm, const float2* __restrict__ tabS,
    const float2* __restrict__ tabL, int Mkv)
{
    int t = blockIdx.x * 256 + threadIdx.x;
    if (t >= Mkv * NHEAD) return;
    int row = t >> 3, h = t & 7;

    int rr = row % TOTAL;
    int l, i, j;
    if (rr < 4096)      { l = 0; i = rr >> 6;               j = rr & 63; }
    else if (rr < 5120) { l = 1; int u = rr - 4096; i = u >> 5; j = u & 31; }
    else if (rr < 5376) { l = 2; int u = rr - 5120; i = u >> 4; j = u & 15; }
    else                { l = 3; int u = rr - 5376; i = u >> 3; j = u & 7;  }

    bf16_t* base = kvm + (size_t)row * (2 * DIM) + h * HDIM;
    bf16x8 xa[3], xb[3];
#pragma unroll
    for (int k = 0; k < 3; ++k) {
        xa[k] = *(const bf16x8*)(base + 8 * k);
        xb[k] = *(const bf16x8*)(base + HALFD + 8 * k);
    }
#pragma unroll
    for (int d = 0; d < HALFD; ++d) {
        float2 cs = (d < 8) ? tabS[i * 8 + d]
                  : (d < 16) ? tabS[j * 8 + (d - 8)]
                             : tabL[l * 8 + (d - 16)];
        float x1 = (float)xa[d >> 3][d & 7];
        float x2 = (float)xb[d >> 3][d & 7];
        xa[d >> 3][d & 7] = (bf16_t)(x1 * cs.x - x2 * cs.y);
        xb[d >> 3][d & 7] = (bf16_t)(x1 * cs.y + x2 * cs.x);
    }
#pragma unroll
    for (int k = 0; k < 3; ++k) {
        *(bf16x8*)(base + 8 * k)         = xa[k];
        *(bf16x8*)(base + HALFD + 8 * k) = xb[k];
    }
}

// ---------------------------------------------------------------------------
// Attention: one block (256 threads) per query — R13-proven structure.
// Queries assigned via spatially-sorted order[]: XCD x serves a compact
// ~half-batch region so re-reads hit its own L2 instead of L3.
// ---------------------------------------------------------------------------
__global__ __launch_bounds__(256) void attn_kernel(
    const float* __restrict__ qproj,   // (N,384) pre-RoPE fp32
    const int*   __restrict__ pos,     // (N,4) b,i,j,l
    const bf16_t* __restrict__ kvm,    // (B*total, 768) bf16, k pre-rotated
    const float2* __restrict__ tabS, const float2* __restrict__ tabL,
    const int* __restrict__ order,     // spatially sorted query ids
    bf16_t* __restrict__ attn_out)     // (N,384) bf16
{
    __shared__ float qs[DIM];
    __shared__ float sc[NHEAD * NKEY];
    __shared__ int   flatL[NKEY], validL[NKEY];
    __shared__ float ptv[5][DIM];

    const int bid = blockIdx.x, tid = threadIdx.x;
    const int n = order[((bid & 7) << 7) | (bid >> 3)];  // XCD-chunked sorted
    const int b  = pos[n * 4 + 0];
    const int qi = pos[n * 4 + 1];
    const int qj = pos[n * 4 + 2];
    const int ql = pos[n * 4 + 3];

    // q RoPE -> qs (threads 0..191)
    if (tid < NHEAD * HALFD) {
        int h = tid / HALFD, d = tid - (tid / HALFD) * HALFD;
        float2 cs = (d < 8) ? tabS[qi * 8 + d]
                  : (d < 16) ? tabS[qj * 8 + (d - 8)]
                             : tabL[ql * 8 + (d - 16)];
        float x1 = qproj[(size_t)n * DIM + h * HDIM + d];
        float x2 = qproj[(size_t)n * DIM + h * HDIM + HALFD + d];
        qs[h * HDIM + d]         = x1 * cs.x - x2 * cs.y;
        qs[h * HDIM + HALFD + d] = x1 * cs.y + x2 * cs.x;
    }

    // per-key geometry, pure integer: center = floor((q+0.5)*2^(ql-l))
    if (tid < NKEY) {
        int kk = tid;
        int l = kk / 49, rem = kk - l * 49;
        int a = rem / 7, bb2 = rem - a * 7;
        int Hl = 64 >> l;
        int off = (l == 0) ? 0 : (l == 1) ? 4096 : (l == 2) ? 5120 : 5376;
        int e = ql - l;
        int ti = 2 * qi + 1, tj = 2 * qj + 1;
        int ci = (e >= 1) ? (ti << (e - 1)) : (ti >> (1 - e));
        int cj = (e >= 1) ? (tj << (e - 1)) : (tj >> (1 - e));
        int ii = ci + a - 3, jj = cj + bb2 - 3;
        int valid = (ii >= 0) && (ii < Hl) && (jj >= 0) && (jj < Hl);
        ii = min(max(ii, 0), Hl - 1); jj = min(max(jj, 0), Hl - 1);
        flatL[kk]  = off + ii * Hl + jj;
        validL[kk] = valid;
    }
    __syncthreads();

    const size_t bbase = (size_t)b * TOTAL;

    // scores: 8 heads x 196 keys
    for (int idx = tid; idx < NHEAD * NKEY; idx += 256) {
        int h = idx / NKEY, kk = idx - h * NKEY;
        const bf16_t* krow = kvm + (bbase + (size_t)flatL[kk]) * (2 * DIM) + h * HDIM;
        bf16x8 kv[6];
#pragma unroll
        for (int i = 0; i < 6; ++i) kv[i] = *(const bf16x8*)(krow + i * 8);
        float dot = 0.f;
#pragma unroll
        for (int i = 0; i < 6; ++i)
#pragma unroll
            for (int e = 0; e < 8; ++e)
                dot += (float)kv[i][e] * qs[h * HDIM + i * 8 + e];
        float score = dot * 0.14433756729740643f;  // 1/sqrt(48)
        if (!validL[kk]) score = -1e9f;
        sc[h * NKEY + kk] = score;
    }
    __syncthreads();

    // softmax: head h handled by threads [h*32, h*32+32)
    {
        int h = tid >> 5, lg = tid & 31;
        float mx = -1e30f;
        for (int j = lg; j < NKEY; j += 32) mx = fmaxf(mx, sc[h * NKEY + j]);
#pragma unroll
        for (int m = 16; m; m >>= 1) mx = fmaxf(mx, __shfl_xor(mx, m));
        float sum = 0.f;
        for (int j = lg; j < NKEY; j += 32) {
            float e = __expf(sc[h * NKEY + j] - mx);
            sc[h * NKEY + j] = e; sum += e;
        }
#pragma unroll
        for (int m = 16; m; m >>= 1) sum += __shfl_xor(sum, m);
        float inv = 1.f / sum;
        for (int j = lg; j < NKEY; j += 32) sc[h * NKEY + j] *= inv;
    }
    __syncthreads();

    // V accumulation: 240 threads = 5 key-groups x 48 dim-octets (16B loads)
    if (tid < 240) {
        int g5 = tid / 48, o = tid - (tid / 48) * 48;  // key-group, dim-octet
        int h = o / 6;                                  // head of this octet
        float a[8];
#pragma unroll
        for (int e = 0; e < 8; ++e) a[e] = 0.f;
        const float* sch = sc + h * NKEY;
#pragma unroll 4
        for (int kk = g5; kk < NKEY; kk += 5) {
            float w = sch[kk];
            bf16x8 vv = *(const bf16x8*)(kvm + (bbase + (size_t)flatL[kk]) * (2 * DIM)
                                         + DIM + 8 * o);
#pragma unroll
            for (int e = 0; e < 8; ++e) a[e] += w * (float)vv[e];
        }
        float4 lo = { a[0], a[1], a[2], a[3] };
        float4 hi = { a[4], a[5], a[6], a[7] };
        *(float4*)(&ptv[g5][8 * o])     = lo;
        *(float4*)(&ptv[g5][8 * o + 4]) = hi;
    }
    __syncthreads();

    // final reduce over key-groups: 192 threads x 2 dims
    if (tid < 192) {
        int d0 = 2 * tid;
        float s0 = 0.f, s1 = 0.f;
#pragma unroll
        for (int g5 = 0; g5 < 5; ++g5) {
            s0 += ptv[g5][d0];
            s1 += ptv[g5][d0 + 1];
        }
        bf16x2 o = { (bf16_t)s0, (bf16_t)s1 };
        *(bf16x2*)(attn_out + (size_t)n * DIM + d0) = o;
    }
}

// ---------------------------------------------------------------------------
extern "C" void kernel_launch(void* const* d_in, const int* in_sizes, int n_in,
                              void* d_out, int out_size, void* d_ws, size_t ws_size,
                              hipStream_t stream)
{
    const float* query  = (const float*)d_in[0];
    const int*   pos    = (const int*)d_in[1];
    const float* fmaps  = (const float*)d_in[3];
    const float* nw     = (const float*)d_in[5];
    const float* nb     = (const float*)d_in[6];
    const float* wq     = (const float*)d_in[7];
    const float* wkv    = (const float*)d_in[8];
    const float* wout   = (const float*)d_in[9];
    float* out = (float*)d_out;

    const int Mkv = in_sizes[3] / DIM;  // B*total = 21760

    char* w = (char*)d_ws;
    auto alloc = [&](size_t bytes) { char* p = w; w += (bytes + 255) & ~(size_t)255; return p; };
    bf16_t* x_ln    = (bf16_t*)alloc((size_t)NQ * DIM * 2);
    float*  qproj   = (float*) alloc((size_t)NQ * DIM * 4);
    bf16_t* attn_o  = (bf16_t*)alloc((size_t)NQ * DIM * 2);
    bf16_t* kvm     = (bf16_t*)alloc((size_t)Mkv * 2 * DIM * 2);
    bf16_t* fm_bf   = (bf16_t*)alloc((size_t)Mkv * DIM * 2);
    bf16_t* wq_bf   = (bf16_t*)alloc((size_t)DIM * DIM * 2);
    bf16_t* wkv_bf  = (bf16_t*)alloc((size_t)2 * DIM * DIM * 2);
    bf16_t* wout_bf = (bf16_t*)alloc((size_t)DIM * DIM * 2);
    float2* tabS    = (float2*)alloc(512 * 8);
    float2* tabL    = (float2*)alloc(32 * 8);
    int*    order   = (int*)alloc((size_t)NQ * 4);

    const int nfm = Mkv * DIM / 4 / 256;   // fmaps cvt blocks (8160)
    prep_kernel<<<nfm + 577 + 256 + 1, 256, 0, stream>>>(
        fmaps, fm_bf, nfm, wq, wkv, wout, wq_bf, wkv_bf, wout_bf, tabS, tabL,
        query, nw, nb, x_ln, pos, order);
    {
        const int n1 = (2 * DIM / 128) * (Mkv / 128);   // 6*170 = 1020 kv blocks
        const int n2 = (DIM / 64) * (NQ / 64);          // 6*16  = 96 qproj blocks
        gemm_dual<<<n1 + n2, 256, 0, stream>>>(
            fm_bf, wkv_bf, (void*)kvm, Mkv, 2 * DIM, DIM, 2 * DIM / 128, n1,
            x_ln, wq_bf, (void*)qproj, NQ, DIM, DIM, DIM / 64, n2);
    }
    rope_k_kernel<<<(Mkv * NHEAD + 255) / 256, 256, 0, stream>>>(kvm, tabS, tabL, Mkv);
    attn_kernel<<<NQ, 256, 0, stream>>>(qproj, pos, kvm, tabS, tabL, order, attn_o);
    gemm_bf16<1, 64><<<dim3(DIM / 64, NQ / 64), 256, 0, stream>>>(
        attn_o, wout_bf, (void*)out, query, NQ, DIM, DIM);
}